// Round 8
// baseline (1937.574 us; speedup 1.0000x reference)
//
#include <hip/hip_runtime.h>
#include <hip/hip_bf16.h>
#include <stdint.h>

// SymmetricHyperRBM on MI355X. K=10 Gibbs chain + free-energy gap.
// fp8 e4m3 everywhere: states (binary -> exact), W/G/cst quantized.
// Rank-64 FiLM biases folded into GEMM K-dim: A'=[state|X|1|pad] (K=1152 B),
// B'=[W|G|cst|pad] -> accumulators ARE logits. dE = -sum z + 2 sum v*z.
// GEMM: 128x128 tile, BK=128, XOR-swizzled LDS (conflict-free fp8 b64 reads),
// global_load_lds staging, XCD-aware swizzle. Zero-reuse streams (old-S,
// sample store-out, cmod) use non-temporal ops so the XCD L2 keeps only
// the reusable A-stripe (2.36 MB, 8x) + B (1.2 MB, 16x) = 3.56 < 4 MB.

#define NB 16384
#define KSTEPS 10
#define LDA 1152           // bytes/row: 1024 state + 64 X + 1 const + 63 pad
#define SLS 136            // epilogue slab row stride in bytes (128 + 8 pad)
#define USALT 4000u
#define ONE8 ((unsigned char)0x38)  // fp8 e4m3 1.0

typedef __attribute__((ext_vector_type(4))) float f32x4;
typedef __attribute__((ext_vector_type(4))) unsigned int u32x4;

__device__ __forceinline__ unsigned hash32(unsigned idx, unsigned salt) {
  unsigned x = idx + salt * 0x9E3779B9u;
  x = (x ^ (x >> 16)) * 0x7feb352du;
  x = (x ^ (x >> 15)) * 0x846ca68bu;
  return x ^ (x >> 16);
}
__device__ __forceinline__ float rng_u01(unsigned salt, unsigned idx) {
  return (float)(hash32(idx, salt) >> 8) * (1.0f / 16777216.0f);
}
// Bernoulli(sigm(z)) with 16-bit uniform f in [0,65536): r<sigm(z) <=> f*e^-z < 65536-f
__device__ __forceinline__ unsigned char bern16(float z, float f) {
  return (f * __expf(-z) < 65536.f - f) ? ONE8 : (unsigned char)0;
}
__device__ __forceinline__ float sigm(float z) { return 1.0f / (1.0f + __expf(-z)); }
__device__ __forceinline__ float softplus_(float z) {
  return z > 0.f ? z + log1pf(__expf(-z)) : log1pf(__expf(z));
}
__device__ __forceinline__ float lse2(float a, float b) {
  float m = fmaxf(a, b);
  return m + log1pf(__expf(fminf(a, b) - m));
}
__device__ __forceinline__ unsigned short f2bf(float f) {
  __hip_bfloat16 h = __float2bfloat16(f);
  return *reinterpret_cast<unsigned short*>(&h);
}
__device__ __forceinline__ float bf2f(unsigned short s) {
  unsigned u = ((unsigned)s) << 16;
  return *reinterpret_cast<float*>(&u);
}
// float -> fp8 e4m3fn (OCP), RNE, saturating. Setup-path only.
__device__ unsigned char f2e4m3(float f) {
  unsigned u = __float_as_uint(f);
  unsigned char s = (unsigned char)((u >> 24) & 0x80);
  float af = fabsf(f);
  if (af >= 448.f) return s | 0x7E;
  float sub = rintf(af * 512.f);
  if (sub < 1.f) return s;                 // underflow -> 0
  if (af < 0.015625f) {                    // subnormal, step 2^-9
    int m = (int)sub;
    if (m > 7) return s | 0x08;
    return s | (unsigned char)m;
  }
  int ex; frexpf(af, &ex);
  int E = ex - 1;                          // af in [2^E, 2^(E+1))
  float q = rintf(ldexpf(af, 3 - E));      // in [8,16]
  int qi = (int)q;
  if (qi >= 16) { qi = 8; E += 1; if (E > 8) return s | 0x7E; }
  return s | (unsigned char)(((E + 7) << 3) | (qi - 8));
}
__device__ __forceinline__ void gl2lds16(const void* g, void* l) {
  __builtin_amdgcn_global_load_lds(
      (const __attribute__((address_space(1))) unsigned int*)g,
      (__attribute__((address_space(3))) unsigned int*)l, 16, 0, 0);
}

// ---------------------------------------------------------------------------
// C[16384 x 1024] = A[16384 x Kdim] * Bt[1024 x Kdim]^T, fp8 MFMA 16x16x32,
// 128x128 tiles, BK=128. LDS: 128-B rows, chunk XOR swizzle sc = q^(row&7).
// 1D grid 1024, XCD-swizzled (xcd=L&7 owns one contiguous m-stripe).
// EPI 0: h = bern(sigm(z)) -> sh (NT store)
// EPI 1: u_t inline; old-S via coalesced NT load -> slab; p0+=sum z,
//        p1+=sum v*z; s_new -> sh (NT store)
// EPI 2: free-energy softplus row sums (mod=cmod bf16 NT; pv0=null -> data)
// ---------------------------------------------------------------------------
template <int EPI>
__global__ __launch_bounds__(256, 4) void gemm_bt(
    const unsigned char* __restrict__ A, const unsigned char* __restrict__ Bt,
    unsigned char* sh, const unsigned short* __restrict__ mod,
    const float* __restrict__ wcs,
    const float* __restrict__ pv0, const float* __restrict__ pv1, unsigned usalt,
    float* __restrict__ p0, float* __restrict__ p1, unsigned salt, int Kdim) {
  // staging: As [0,16K) Bs [16K,32K); epilogue: oldsl [0,8.7K) newsl [9.2K,18K)
  __shared__ __align__(16) char smem[32768];
  unsigned char* sm8 = (unsigned char*)smem;
  unsigned char* oldsl = sm8;
  unsigned char* newsl = sm8 + 9216;

  const int t = threadIdx.x;
  const int L = blockIdx.x;
  const int xcd = L & 7, li = L >> 3;
  const int m0 = (xcd * 16 + (li >> 3)) * 128;
  const int n0 = (li & 7) * 128;
  const int lane = t & 63, wave = t >> 6;
  const int wm = (wave >> 1) * 64, wn = (wave & 1) * 64;
  const int lr = lane & 15, quad = lane >> 4;
  // staging: lane -> row i>>3, phys chunk i&7, gathers LOGICAL chunk (i&7)^(i>>3)
  const int srow = lane >> 3;
  const int sq16 = (((lane & 7) ^ srow) << 4);
  // fragment read offsets: logical chunk s*2+(quad>>1), row-xor lr&7
  const int ql8 = (quad & 1) * 8, qh = quad >> 1, lx = lr & 7;
  int koff[4];
#pragma unroll
  for (int s = 0; s < 4; ++s) koff[s] = (((s * 2 + qh) ^ lx) << 4) + ql8;

  f32x4 acc[4][4] = {};

  for (int k0 = 0; k0 < Kdim; k0 += 128) {
#pragma unroll
    for (int c = 0; c < 4; ++c) {
      const int wgrp = wave * 4 + c;      // 16 groups of 8 rows
      const int row = wgrp * 8 + srow;
      gl2lds16(A + (size_t)(m0 + row) * LDA + k0 + sq16, smem + wgrp * 1024);
      gl2lds16(Bt + (size_t)(n0 + row) * LDA + k0 + sq16, smem + 16384 + wgrp * 1024);
    }
    __syncthreads();
#pragma unroll
    for (int s = 0; s < 4; ++s) {  // four K=32 slices of the 128-B row
      long af[4], bfr[4];
#pragma unroll
      for (int i = 0; i < 4; i++)
        af[i] = *(const long*)(smem + (wm + i * 16 + lr) * 128 + koff[s]);
#pragma unroll
      for (int j = 0; j < 4; j++)
        bfr[j] = *(const long*)(smem + 16384 + (wn + j * 16 + lr) * 128 + koff[s]);
#pragma unroll
      for (int i = 0; i < 4; i++)
#pragma unroll
        for (int j = 0; j < 4; j++)
          acc[i][j] = __builtin_amdgcn_mfma_f32_16x16x32_fp8_fp8(af[i], bfr[j], acc[i][j], 0, 0, 0);
    }
    __syncthreads();
  }

  // C/D layout (m89, dtype-independent): col = lane&15, row = quad*4 + reg
  if constexpr (EPI == 2) {
#pragma unroll
    for (int i = 0; i < 4; i++)
#pragma unroll
      for (int rg = 0; rg < 4; rg++) {
        const int r = m0 + wm + i * 16 + quad * 4 + rg;
        bool uu = true;
        if (pv0 != nullptr) {
          const float dE = -pv0[r] + 2.f * pv1[r];
          uu = rng_u01(usalt, (unsigned)r) < sigm(dE);
        }
        float sn = 0.f, sf = 0.f;
#pragma unroll
        for (int j = 0; j < 4; j++) {
          const int n = n0 + wn + j * 16 + lr;
          const float vw = acc[i][j][rg];
          const float cm = bf2f(__builtin_nontemporal_load(mod + (size_t)r * 1024 + n));
          const float s1 = softplus_(vw + cm);
          const float s2 = softplus_(wcs[n] - vw + cm);
          sn += uu ? s1 : s2;
          sf += uu ? s2 : s1;
        }
#pragma unroll
        for (int msk = 1; msk < 16; msk <<= 1) {
          sn += __shfl_xor(sn, msk, 64);
          sf += __shfl_xor(sf, msk, 64);
        }
        if (lr == 0) { atomicAdd(&p0[r], sn); atomicAdd(&p1[r], sf); }
      }
    return;
  }

  // EPI 0/1: reduction (EPI1) + sample + repack through LDS -> NT stores
  const int myphase = wm >> 6;  // waves 0,1 -> rows 0..63 ; waves 2,3 -> 64..127
#pragma unroll
  for (int ph = 0; ph < 2; ++ph) {
    if constexpr (EPI == 1) {  // coalesced NT load of old S into slab
#pragma unroll
      for (int p = 0; p < 2; ++p) {
        const int c = p * 256 + t, rowl = c >> 3, chk = c & 7;
        const u32x4 vv = __builtin_nontemporal_load(
            (const u32x4*)(sh + (size_t)(m0 + ph * 64 + rowl) * LDA + n0 + chk * 16));
        *(u32x4*)(oldsl + rowl * SLS + chk * 16) = vv;
      }
      __syncthreads();
    }
    if (myphase == ph) {
#pragma unroll
      for (int i = 0; i < 4; ++i)
#pragma unroll
        for (int rg = 0; rg < 4; ++rg) {
          const int rowl = i * 16 + quad * 4 + rg;  // 0..63 within phase
          const int r = m0 + wm + rowl;
          if constexpr (EPI == 1) {  // z-sums with v from OLD s; u_t inline
            const float dE = -pv0[r] + 2.f * pv1[r];
            const bool uu = rng_u01(usalt, (unsigned)r) < sigm(dE);
            float q0 = 0.f, q1 = 0.f;
#pragma unroll
            for (int j = 0; j < 4; ++j) {
              const float z = acc[i][j][rg];
              const float so = (oldsl[rowl * SLS + wn + j * 16 + lr] != 0) ? 1.f : 0.f;
              const float v = uu ? so : 1.f - so;
              q0 += z; q1 += v * z;
            }
#pragma unroll
            for (int msk = 1; msk < 16; msk <<= 1) {
              q0 += __shfl_xor(q0, msk, 64);
              q1 += __shfl_xor(q1, msk, 64);
            }
            if (lr == 0) { atomicAdd(&p0[r], q0); atomicAdd(&p1[r], q1); }
          }
#pragma unroll
          for (int jp = 0; jp < 2; ++jp) {
            const unsigned x =
                hash32((unsigned)(r << 10) + (unsigned)(n0 + wn + jp * 16 + lr), salt);
            const float flo = (float)(x & 0xFFFFu), fhi = (float)(x >> 16);
            newsl[rowl * SLS + wn + jp * 16 + lr] = bern16(acc[i][jp][rg], flo);
            newsl[rowl * SLS + wn + (jp + 2) * 16 + lr] = bern16(acc[i][jp + 2][rg], fhi);
          }
        }
    }
    __syncthreads();
#pragma unroll
    for (int p = 0; p < 2; ++p) {  // 64 rows x 128 B, fully coalesced NT store
      const int c = p * 256 + t, rowl = c >> 3, chk = c & 7;
      const u32x4 vv = *(const u32x4*)(newsl + rowl * SLS + chk * 16);
      __builtin_nontemporal_store(
          vv, (u32x4*)(sh + (size_t)(m0 + ph * 64 + rowl) * LDA + n0 + chk * 16));
    }
    __syncthreads();
  }
}

// ------------------------- setup / small kernels ---------------------------
__global__ __launch_bounds__(256) void k_x(const float* __restrict__ cond,
                                           const float* __restrict__ fc1w,
                                           const float* __restrict__ fc1b, float* __restrict__ X) {
  int idx = blockIdx.x * 256 + threadIdx.x;
  int r = idx >> 6, k = idx & 63;
  X[idx] = tanhf(cond[r] * fc1w[k] + fc1b[k]);
}

__global__ __launch_bounds__(256) void k_g(const float* __restrict__ fc2w,
                                           const float* __restrict__ fc2b,
                                           const float* __restrict__ b, const float* __restrict__ c,
                                           float* __restrict__ Gb, float* __restrict__ Gc,
                                           float* __restrict__ cstb, float* __restrict__ cstc) {
  int idx = blockIdx.x * 256 + threadIdx.x;
  int j = idx >> 6, k = idx & 63;
  Gb[idx] = fc2w[(size_t)j * 64 + k] * b[j] + fc2w[(size_t)(1024 + j) * 64 + k];
  Gc[idx] = fc2w[(size_t)(2048 + j) * 64 + k] * c[j] + fc2w[(size_t)(3072 + j) * 64 + k];
  if (k == 0) {
    cstb[j] = b[j] + fc2b[j] * b[j] + fc2b[1024 + j];
    cstc[j] = c[j] + fc2b[2048 + j] * c[j] + fc2b[3072 + j];
  }
}

__global__ __launch_bounds__(256) void k_prep(const float* __restrict__ W,
                                              const float* __restrict__ Gb,
                                              const float* __restrict__ Gc,
                                              const float* __restrict__ cstb,
                                              const float* __restrict__ cstc,
                                              unsigned char* __restrict__ Wt,
                                              unsigned char* __restrict__ Wb) {
  int k = blockIdx.x * 256 + threadIdx.x;
  int n = blockIdx.y;
  if (k >= LDA) return;
  unsigned char wt, wb;
  if (k < 1024) {
    wt = f2e4m3(W[(size_t)k * 1024 + n]);
    wb = f2e4m3(W[(size_t)n * 1024 + k]);
  } else if (k < 1088) {
    int j = k - 1024;
    wt = f2e4m3(Gc[(size_t)n * 64 + j]);
    wb = f2e4m3(Gb[(size_t)n * 64 + j]);
  } else if (k == 1088) {
    wt = f2e4m3(cstc[n]);
    wb = f2e4m3(cstb[n]);
  } else { wt = 0; wb = 0; }
  Wt[(size_t)n * LDA + k] = wt;
  Wb[(size_t)n * LDA + k] = wb;
}

__global__ __launch_bounds__(256) void k_wcs(const float* __restrict__ W, float* __restrict__ wcs) {
  int n = blockIdx.x * 256 + threadIdx.x;
  float s = 0.f;
  for (int i = 0; i < 1024; i++) s += W[(size_t)i * 1024 + n];
  wcs[n] = s;
}

// out[128 x 128] = X @ G^T + cst, stored bf16 (free-energy path stays accurate)
__global__ __launch_bounds__(256) void k_bmod(const float* __restrict__ X,
                                              const float* __restrict__ G,
                                              const float* __restrict__ cst,
                                              unsigned short* __restrict__ out) {
  __shared__ __align__(16) float Xs[128 * 64];
  __shared__ __align__(16) float Gs[128 * 64];
  const int t = threadIdx.x;
  const int r0 = blockIdx.x * 128, c0 = blockIdx.y * 128;
#pragma unroll
  for (int c = 0; c < 8; ++c) {
    int i4 = c * 256 + t;
    ((float4*)Xs)[i4] = ((const float4*)(X + (size_t)r0 * 64))[i4];
    ((float4*)Gs)[i4] = ((const float4*)(G + (size_t)c0 * 64))[i4];
  }
  __syncthreads();
  const int tr = (t >> 4) * 8, tc = (t & 15) * 8;
  float acc[8][8] = {};
  for (int k = 0; k < 64; k += 4) {
    float4 xa[8], gb[8];
#pragma unroll
    for (int i = 0; i < 8; i++) xa[i] = *(const float4*)(Xs + (tr + i) * 64 + k);
#pragma unroll
    for (int j = 0; j < 8; j++) gb[j] = *(const float4*)(Gs + (tc + j) * 64 + k);
#pragma unroll
    for (int i = 0; i < 8; i++)
#pragma unroll
      for (int j = 0; j < 8; j++)
        acc[i][j] += xa[i].x * gb[j].x + xa[i].y * gb[j].y + xa[i].z * gb[j].z + xa[i].w * gb[j].w;
  }
#pragma unroll
  for (int i = 0; i < 8; i++)
#pragma unroll
    for (int j = 0; j < 8; j++)
      out[(size_t)(r0 + tr + i) * 1024 + (c0 + tc + j)] = f2bf(acc[i][j] + cst[c0 + tc + j]);
}

__global__ __launch_bounds__(256) void k_sinit(const float* __restrict__ vdata,
                                               const float* __restrict__ X,
                                               unsigned char* __restrict__ S,
                                               unsigned char* __restrict__ H,
                                               unsigned char* __restrict__ V) {
  int k = blockIdx.x * 256 + threadIdx.x;
  int r = blockIdx.y;
  if (k >= LDA) return;
  const size_t o = (size_t)r * LDA + k;
  if (k < 1024) {
    float vd = vdata[(size_t)r * 1024 + k];
    V[o] = (vd != 0.f) ? ONE8 : (unsigned char)0;
    const bool u0 = rng_u01(USALT, (unsigned)r) < 0.5f;  // == EPI1 step-0 formula
    float sv = u0 ? vd : 1.f - vd;
    S[o] = (sv != 0.f) ? ONE8 : (unsigned char)0;
  } else {
    unsigned char xv;
    if (k < 1088) xv = f2e4m3(X[(size_t)r * 64 + (k - 1024)]);
    else if (k == 1088) xv = ONE8;  // 1.0
    else xv = 0;
    S[o] = xv; H[o] = xv;
  }
}

__global__ __launch_bounds__(256) void k_final(
    const unsigned char* __restrict__ V, const unsigned char* __restrict__ S,
    const unsigned short* __restrict__ bmod,
    const float* __restrict__ pv0, const float* __restrict__ pv1, unsigned usalt,
    const float* __restrict__ spn_d, const float* __restrict__ spf_d,
    const float* __restrict__ spn_m, const float* __restrict__ spf_m, float* __restrict__ fdiff) {
  __shared__ float red0[4], red1[4], red2[4];
  int r = blockIdx.x, t = threadIdx.x;
  const unsigned short* brow = bmod + (size_t)r * 1024;
  const unsigned char* vrow = V + (size_t)r * LDA;
  const unsigned char* srow = S + (size_t)r * LDA;
  float d0 = 0.f, d1 = 0.f, d2 = 0.f;
  for (int j = t; j < 1024; j += 256) {
    float bm = bf2f(brow[j]);
    d0 += bm;
    d1 += (vrow[j] != 0) ? bm : 0.f;
    d2 += (srow[j] != 0) ? bm : 0.f;
  }
  for (int m = 32; m >= 1; m >>= 1) {
    d0 += __shfl_xor(d0, m, 64);
    d1 += __shfl_xor(d1, m, 64);
    d2 += __shfl_xor(d2, m, 64);
  }
  if ((t & 63) == 0) { red0[t >> 6] = d0; red1[t >> 6] = d1; red2[t >> 6] = d2; }
  __syncthreads();
  if (t == 0) {
    d0 = red0[0] + red0[1] + red0[2] + red0[3];
    d1 = red1[0] + red1[1] + red1[2] + red1[3];
    d2 = red2[0] + red2[1] + red2[2] + red2[3];
    const float dE = -pv0[r] + 2.f * pv1[r];
    const bool uu = rng_u01(usalt, (unsigned)r) < sigm(dE);
    float Fn_d = -d1 - spn_d[r];
    float Ff_d = -(d0 - d1) - spf_d[r];
    float F_d = -lse2(-Fn_d, -Ff_d);
    float vbn = uu ? d2 : (d0 - d2);
    float Fn_m = -vbn - spn_m[r];
    float Ff_m = -(d0 - vbn) - spf_m[r];
    float F_m = -lse2(-Fn_m, -Ff_m);
    fdiff[r] = F_d - F_m;
  }
}

__global__ __launch_bounds__(256) void k_reduce(const float* __restrict__ fdiff,
                                                float* __restrict__ out) {
  __shared__ float red[4];
  int t = threadIdx.x;
  float s = 0.f;
  for (int i = t; i < NB; i += 256) s += fdiff[i];
  for (int m = 32; m >= 1; m >>= 1) s += __shfl_xor(s, m, 64);
  if ((t & 63) == 0) red[t >> 6] = s;
  __syncthreads();
  if (t == 0) out[0] = (red[0] + red[1] + red[2] + red[3]) * (1.0f / (float)NB);
}

// ---------------------------------------------------------------------------
extern "C" void kernel_launch(void* const* d_in, const int* in_sizes, int n_in, void* d_out,
                              int out_size, void* d_ws, size_t ws_size, hipStream_t stream) {
  const float* vdata = (const float*)d_in[0];
  const float* cond = (const float*)d_in[1];
  const float* W = (const float*)d_in[2];
  const float* bb = (const float*)d_in[3];
  const float* cc = (const float*)d_in[4];
  const float* fc1w = (const float*)d_in[5];
  const float* fc1b = (const float*)d_in[6];
  const float* fc2w = (const float*)d_in[7];
  const float* fc2b = (const float*)d_in[8];
  float* out = (float*)d_out;

  char* wp = (char*)d_ws;
  auto alloc = [&](size_t bytes) {
    char* p = wp;
    wp += (bytes + 255) & ~(size_t)255;
    return p;
  };
  unsigned char* Wt = (unsigned char*)alloc((size_t)1024 * LDA);
  unsigned char* Wb = (unsigned char*)alloc((size_t)1024 * LDA);
  float* wcs = (float*)alloc(1024 * 4);
  float* X = (float*)alloc((size_t)NB * 64 * 4);
  float* Gb = (float*)alloc((size_t)1024 * 64 * 4);
  float* Gc = (float*)alloc((size_t)1024 * 64 * 4);
  float* cstb = (float*)alloc(1024 * 4);
  float* cstc = (float*)alloc(1024 * 4);
  unsigned short* bmod = (unsigned short*)alloc((size_t)NB * 1024 * 2);
  unsigned short* cmod = (unsigned short*)alloc((size_t)NB * 1024 * 2);
  unsigned char* S = (unsigned char*)alloc((size_t)NB * LDA);
  unsigned char* H = (unsigned char*)alloc((size_t)NB * LDA);
  unsigned char* V = (unsigned char*)alloc((size_t)NB * LDA);
  // per-step dE accumulators: pair t stored at pall + (t+1)*2*NB, t = -1..9
  float* pall = (float*)alloc((size_t)(KSTEPS + 1) * 2 * NB * 4);
  float* spn_d = (float*)alloc(NB * 4);  // contiguous with spf_d/spn_m/spf_m
  float* spf_d = (float*)alloc(NB * 4);
  float* spn_m = (float*)alloc(NB * 4);
  float* spf_m = (float*)alloc(NB * 4);
  float* fdiff = (float*)alloc(NB * 4);
  auto P0 = [&](int t) { return pall + (size_t)(t + 1) * 2 * NB; };
  auto P1 = [&](int t) { return pall + (size_t)(t + 1) * 2 * NB + NB; };

  hipMemsetAsync(pall, 0, (size_t)(KSTEPS + 1) * 2 * NB * 4 + (size_t)4 * NB * 4, stream);

  k_x<<<NB * 64 / 256, 256, 0, stream>>>(cond, fc1w, fc1b, X);
  k_g<<<1024 * 64 / 256, 256, 0, stream>>>(fc2w, fc2b, bb, cc, Gb, Gc, cstb, cstc);
  k_prep<<<dim3(5, 1024), 256, 0, stream>>>(W, Gb, Gc, cstb, cstc, Wt, Wb);
  k_wcs<<<4, 256, 0, stream>>>(W, wcs);
  dim3 bgrid(NB / 128, 1024 / 128);
  k_bmod<<<bgrid, 256, 0, stream>>>(X, Gb, cstb, bmod);
  k_bmod<<<bgrid, 256, 0, stream>>>(X, Gc, cstc, cmod);
  k_sinit<<<dim3(5, NB), 256, 0, stream>>>(vdata, X, S, H, V);

  for (int step = 0; step < KSTEPS; ++step) {
    // z1 = sW + c_mod (ext-K); h ~ Bern(sigm(z1)) -> H
    gemm_bt<0><<<1024, 256, 0, stream>>>(S, Wt, H, nullptr, nullptr, nullptr, nullptr, 0u,
                                         nullptr, nullptr, 2000u + (unsigned)step, LDA);
    // z2 = hW^T + b_mod (ext-K); u_t inline from step-1 sums; dE partials -> step t;
    // s_new ~ Bern(sigm(z2)) -> S
    gemm_bt<1><<<1024, 256, 0, stream>>>(H, Wb, S, nullptr, nullptr, P0(step - 1), P1(step - 1),
                                         USALT + (unsigned)step, P0(step), P1(step),
                                         3000u + (unsigned)step, LDA);
  }

  // Free-energy softplus sums (K=1024 plain vW + cmod read). Data pass u=1; model
  // pass computes u_K inline from step K-1 sums.
  gemm_bt<2><<<1024, 256, 0, stream>>>(V, Wt, nullptr, cmod, wcs, nullptr, nullptr, 0u,
                                       spn_d, spf_d, 0u, 1024);
  gemm_bt<2><<<1024, 256, 0, stream>>>(S, Wt, nullptr, cmod, wcs, P0(KSTEPS - 1), P1(KSTEPS - 1),
                                       USALT + KSTEPS, spn_m, spf_m, 0u, 1024);
  k_final<<<NB, 256, 0, stream>>>(V, S, bmod, P0(KSTEPS - 1), P1(KSTEPS - 1), USALT + KSTEPS,
                                  spn_d, spf_d, spn_m, spf_m, fdiff);
  k_reduce<<<1, 256, 0, stream>>>(fdiff, out);
}

// Round 9
// 1718.155 us; speedup vs baseline: 1.1277x; 1.1277x over previous
//
#include <hip/hip_runtime.h>
#include <hip/hip_bf16.h>
#include <stdint.h>

// SymmetricHyperRBM on MI355X. K=10 Gibbs chain + free-energy gap.
// fp8 e4m3: states binary->exact, W/G/cst quantized. FiLM biases folded into
// GEMM K-dim (A'=[state|X|1|pad], B'=[W|G|cst|pad]); dE = -sum z + 2 sum v*z.
// GEMM: 128x128, BK=128, XOR-swizzled LDS, global_load_lds, XCD swizzle.
// Free-energy b_mod dots via 65 extra N-cols on the EPI2 gemm (no bmod array).
// Single-barrier epilogue. S/H stores regular (they're the next gemm's A!).

#define NB 16384
#define KSTEPS 10
#define LDA 1152           // bytes/row: 1024 state + 64 X + 1 const + 63 pad
#define SLS 136            // epilogue slab row stride in bytes (128 + 8 pad)
#define USALT 4000u
#define ONE8 ((unsigned char)0x38)  // fp8 e4m3 1.0

typedef __attribute__((ext_vector_type(4))) float f32x4;
typedef __attribute__((ext_vector_type(4))) unsigned int u32x4;

__device__ __forceinline__ unsigned hash32(unsigned idx, unsigned salt) {
  unsigned x = idx + salt * 0x9E3779B9u;
  x = (x ^ (x >> 16)) * 0x7feb352du;
  x = (x ^ (x >> 15)) * 0x846ca68bu;
  return x ^ (x >> 16);
}
__device__ __forceinline__ float rng_u01(unsigned salt, unsigned idx) {
  return (float)(hash32(idx, salt) >> 8) * (1.0f / 16777216.0f);
}
// Bernoulli(sigm(z)) with 16-bit uniform f in [0,65536): r<sigm(z) <=> f*e^-z < 65536-f
__device__ __forceinline__ unsigned char bern16(float z, float f) {
  return (f * __expf(-z) < 65536.f - f) ? ONE8 : (unsigned char)0;
}
__device__ __forceinline__ float sigm(float z) { return 1.0f / (1.0f + __expf(-z)); }
__device__ __forceinline__ float softplus_(float z) {
  return z > 0.f ? z + log1pf(__expf(-z)) : log1pf(__expf(z));
}
__device__ __forceinline__ float lse2(float a, float b) {
  float m = fmaxf(a, b);
  return m + log1pf(__expf(fminf(a, b) - m));
}
__device__ __forceinline__ float bf2f(unsigned short s) {
  unsigned u = ((unsigned)s) << 16;
  return *reinterpret_cast<float*>(&u);
}
__device__ __forceinline__ unsigned short f2bf(float f) {
  __hip_bfloat16 h = __float2bfloat16(f);
  return *reinterpret_cast<unsigned short*>(&h);
}
// float -> fp8 e4m3fn (OCP), RNE, saturating. Setup-path only.
__device__ unsigned char f2e4m3(float f) {
  unsigned u = __float_as_uint(f);
  unsigned char s = (unsigned char)((u >> 24) & 0x80);
  float af = fabsf(f);
  if (af >= 448.f) return s | 0x7E;
  float sub = rintf(af * 512.f);
  if (sub < 1.f) return s;                 // underflow -> 0
  if (af < 0.015625f) {                    // subnormal, step 2^-9
    int m = (int)sub;
    if (m > 7) return s | 0x08;
    return s | (unsigned char)m;
  }
  int ex; frexpf(af, &ex);
  int E = ex - 1;                          // af in [2^E, 2^(E+1))
  float q = rintf(ldexpf(af, 3 - E));      // in [8,16]
  int qi = (int)q;
  if (qi >= 16) { qi = 8; E += 1; if (E > 8) return s | 0x7E; }
  return s | (unsigned char)(((E + 7) << 3) | (qi - 8));
}
__device__ __forceinline__ void gl2lds16(const void* g, void* l) {
  __builtin_amdgcn_global_load_lds(
      (const __attribute__((address_space(1))) unsigned int*)g,
      (__attribute__((address_space(3))) unsigned int*)l, 16, 0, 0);
}

// ---------------------------------------------------------------------------
// C = A[16384 x Kdim] * Bt[N x Kdim]^T, fp8 MFMA 16x16x32, 128x128, BK=128.
// Block map: xcd=L&7, li=L>>3; m-tile = xcd*16 + (li&15); n-tile = li>>4.
// EPI 0: h = bern(sigm(z)) -> sh (slab repack, 1 barrier)
// EPI 1: u_t inline; old-S scattered L2 reads; p0+=sum z, p1+=sum v*z;
//        s_new -> sh (slab repack, 1 barrier)
// EPI 2: n-tile<8: softplus rows (cmod NT) -> p0/p1; n-tile 8: v.bmod -> p2
// ---------------------------------------------------------------------------
template <int EPI>
__global__ __launch_bounds__(256, 4) void gemm_bt(
    const unsigned char* __restrict__ A, const unsigned char* __restrict__ Bt,
    unsigned char* sh, const unsigned short* __restrict__ mod,
    const float* __restrict__ wcs, const float* __restrict__ Xf,
    const float* __restrict__ pv0, const float* __restrict__ pv1, unsigned usalt,
    float* __restrict__ p0, float* __restrict__ p1, float* __restrict__ p2,
    unsigned salt, int Kdim) {
  // staging: As [0,16K) Bs [16K,32K); epilogue slab 128 x 136 B aliases front
  __shared__ __align__(16) char smem[32768];
  unsigned char* newsl = (unsigned char*)smem;

  const int t = threadIdx.x;
  const int L = blockIdx.x;
  const int xcd = L & 7, li = L >> 3;
  const int m0 = (xcd * 16 + (li & 15)) * 128;
  const int n0 = (li >> 4) * 128;
  const int lane = t & 63, wave = t >> 6;
  const int wm = (wave >> 1) * 64, wn = (wave & 1) * 64;
  const int lr = lane & 15, quad = lane >> 4;
  // staging: lane -> row i>>3, phys chunk i&7, gathers LOGICAL chunk (i&7)^(i>>3)
  const int srow = lane >> 3;
  const int sq16 = (((lane & 7) ^ srow) << 4);
  // fragment read offsets: logical chunk s*2+(quad>>1), row-xor lr&7
  const int ql8 = (quad & 1) * 8, qh = quad >> 1, lx = lr & 7;
  int koff[4];
#pragma unroll
  for (int s = 0; s < 4; ++s) koff[s] = (((s * 2 + qh) ^ lx) << 4) + ql8;

  f32x4 acc[4][4] = {};

  for (int k0 = 0; k0 < Kdim; k0 += 128) {
#pragma unroll
    for (int c = 0; c < 4; ++c) {
      const int wgrp = wave * 4 + c;      // 16 groups of 8 rows
      const int row = wgrp * 8 + srow;
      gl2lds16(A + (size_t)(m0 + row) * LDA + k0 + sq16, smem + wgrp * 1024);
      gl2lds16(Bt + (size_t)(n0 + row) * LDA + k0 + sq16, smem + 16384 + wgrp * 1024);
    }
    __syncthreads();
#pragma unroll
    for (int s = 0; s < 4; ++s) {  // four K=32 slices of the 128-B row
      long af[4], bfr[4];
#pragma unroll
      for (int i = 0; i < 4; i++)
        af[i] = *(const long*)(smem + (wm + i * 16 + lr) * 128 + koff[s]);
#pragma unroll
      for (int j = 0; j < 4; j++)
        bfr[j] = *(const long*)(smem + 16384 + (wn + j * 16 + lr) * 128 + koff[s]);
#pragma unroll
      for (int i = 0; i < 4; i++)
#pragma unroll
        for (int j = 0; j < 4; j++)
          acc[i][j] = __builtin_amdgcn_mfma_f32_16x16x32_fp8_fp8(af[i], bfr[j], acc[i][j], 0, 0, 0);
    }
    __syncthreads();
  }

  // C/D layout (m89, dtype-independent): col = lane&15, row = quad*4 + reg
  if constexpr (EPI == 2) {
    if (n0 >= 1024) {  // bias-dot tile: acc cols = [Gb-dots | cstb-dot | pad]
#pragma unroll
      for (int i = 0; i < 4; i++)
#pragma unroll
        for (int rg = 0; rg < 4; rg++) {
          const int r = m0 + wm + i * 16 + quad * 4 + rg;
          float pb = 0.f;
          if (wn == 0) {  // cols 1024..1087: Gb-dots, dot with X[r]
#pragma unroll
            for (int j = 0; j < 4; j++)
              pb += acc[i][j][rg] * Xf[(size_t)r * 64 + lr + 16 * j];
          } else {        // col 1088 (lr==0): v.cstb
            if (lr == 0) pb = acc[i][0][rg];
          }
#pragma unroll
          for (int msk = 1; msk < 16; msk <<= 1) pb += __shfl_xor(pb, msk, 64);
          if (lr == 0) atomicAdd(&p2[r], pb);
        }
      return;
    }
#pragma unroll
    for (int i = 0; i < 4; i++)
#pragma unroll
      for (int rg = 0; rg < 4; rg++) {
        const int r = m0 + wm + i * 16 + quad * 4 + rg;
        bool uu = true;
        if (pv0 != nullptr) {
          const float dE = -pv0[r] + 2.f * pv1[r];
          uu = rng_u01(usalt, (unsigned)r) < sigm(dE);
        }
        float sn = 0.f, sf = 0.f;
#pragma unroll
        for (int j = 0; j < 4; j++) {
          const int n = n0 + wn + j * 16 + lr;
          const float vw = acc[i][j][rg];
          const float cm = bf2f(__builtin_nontemporal_load(mod + (size_t)r * 1024 + n));
          const float s1 = softplus_(vw + cm);
          const float s2 = softplus_(wcs[n] - vw + cm);
          sn += uu ? s1 : s2;
          sf += uu ? s2 : s1;
        }
#pragma unroll
        for (int msk = 1; msk < 16; msk <<= 1) {
          sn += __shfl_xor(sn, msk, 64);
          sf += __shfl_xor(sf, msk, 64);
        }
        if (lr == 0) { atomicAdd(&p0[r], sn); atomicAdd(&p1[r], sf); }
      }
    return;
  }

  // EPI 0/1: reduction (EPI1) + sample into full 128-row slab, 1 barrier, store
#pragma unroll
  for (int i = 0; i < 4; ++i)
#pragma unroll
    for (int rg = 0; rg < 4; ++rg) {
      const int rowl = wm + i * 16 + quad * 4 + rg;  // 0..127 in tile
      const int r = m0 + rowl;
      if constexpr (EPI == 1) {  // z-sums with v from OLD s (scattered L2 reads)
        const float dE = -pv0[r] + 2.f * pv1[r];
        const bool uu = rng_u01(usalt, (unsigned)r) < sigm(dE);
        float q0 = 0.f, q1 = 0.f;
#pragma unroll
        for (int j = 0; j < 4; ++j) {
          const float z = acc[i][j][rg];
          const float so = (sh[(size_t)r * LDA + n0 + wn + j * 16 + lr] != 0) ? 1.f : 0.f;
          const float v = uu ? so : 1.f - so;
          q0 += z; q1 += v * z;
        }
#pragma unroll
        for (int msk = 1; msk < 16; msk <<= 1) {
          q0 += __shfl_xor(q0, msk, 64);
          q1 += __shfl_xor(q1, msk, 64);
        }
        if (lr == 0) { atomicAdd(&p0[r], q0); atomicAdd(&p1[r], q1); }
      }
#pragma unroll
      for (int jp = 0; jp < 2; ++jp) {
        const unsigned x = hash32((unsigned)(r << 10) + (unsigned)(n0 + wn + jp * 16 + lr), salt);
        const float flo = (float)(x & 0xFFFFu), fhi = (float)(x >> 16);
        newsl[rowl * SLS + wn + jp * 16 + lr] = bern16(acc[i][jp][rg], flo);
        newsl[rowl * SLS + wn + (jp + 2) * 16 + lr] = bern16(acc[i][jp + 2][rg], fhi);
      }
    }
  __syncthreads();
#pragma unroll
  for (int p = 0; p < 4; ++p) {  // 128 rows x 128 B, fully coalesced
    const int c = p * 256 + t, rowl = c >> 3, chk = c & 7;
    const u32x4 vv = *(const u32x4*)(newsl + rowl * SLS + chk * 16);
    *(u32x4*)(sh + (size_t)(m0 + rowl) * LDA + n0 + chk * 16) = vv;
  }
}

// ------------------------- setup / small kernels ---------------------------
__global__ __launch_bounds__(256) void k_x(const float* __restrict__ cond,
                                           const float* __restrict__ fc1w,
                                           const float* __restrict__ fc1b, float* __restrict__ X) {
  int idx = blockIdx.x * 256 + threadIdx.x;
  int r = idx >> 6, k = idx & 63;
  X[idx] = tanhf(cond[r] * fc1w[k] + fc1b[k]);
}

__global__ __launch_bounds__(256) void k_g(const float* __restrict__ fc2w,
                                           const float* __restrict__ fc2b,
                                           const float* __restrict__ b, const float* __restrict__ c,
                                           float* __restrict__ Gb, float* __restrict__ Gc,
                                           float* __restrict__ cstb, float* __restrict__ cstc) {
  int idx = blockIdx.x * 256 + threadIdx.x;
  int j = idx >> 6, k = idx & 63;
  Gb[idx] = fc2w[(size_t)j * 64 + k] * b[j] + fc2w[(size_t)(1024 + j) * 64 + k];
  Gc[idx] = fc2w[(size_t)(2048 + j) * 64 + k] * c[j] + fc2w[(size_t)(3072 + j) * 64 + k];
  if (k == 0) {
    cstb[j] = b[j] + fc2b[j] * b[j] + fc2b[1024 + j];
    cstc[j] = c[j] + fc2b[2048 + j] * c[j] + fc2b[3072 + j];
  }
}

// Wt: 1152 rows = [W^T|Gc|cstc|pad] cols 0..1023, then rows 1024..1087 = Gb-col
// profiles, row 1088 = cstb profile (first-1024 K only). Wb: 1024 rows.
__global__ __launch_bounds__(256) void k_prep(const float* __restrict__ W,
                                              const float* __restrict__ Gb,
                                              const float* __restrict__ Gc,
                                              const float* __restrict__ cstb,
                                              const float* __restrict__ cstc,
                                              unsigned char* __restrict__ Wt,
                                              unsigned char* __restrict__ Wb) {
  int k = blockIdx.x * 256 + threadIdx.x;
  int n = blockIdx.y;
  if (k >= LDA) return;
  if (n < 1024) {
    unsigned char wt, wb;
    if (k < 1024) {
      wt = f2e4m3(W[(size_t)k * 1024 + n]);
      wb = f2e4m3(W[(size_t)n * 1024 + k]);
    } else if (k < 1088) {
      int j = k - 1024;
      wt = f2e4m3(Gc[(size_t)n * 64 + j]);
      wb = f2e4m3(Gb[(size_t)n * 64 + j]);
    } else if (k == 1088) {
      wt = f2e4m3(cstc[n]);
      wb = f2e4m3(cstb[n]);
    } else { wt = 0; wb = 0; }
    Wt[(size_t)n * LDA + k] = wt;
    Wb[(size_t)n * LDA + k] = wb;
  } else {
    unsigned char wt = 0;
    if (k < 1024) {
      if (n < 1088) wt = f2e4m3(Gb[(size_t)k * 64 + (n - 1024)]);
      else if (n == 1088) wt = f2e4m3(cstb[k]);
    }
    Wt[(size_t)n * LDA + k] = wt;
  }
}

__global__ __launch_bounds__(256) void k_wcs(const float* __restrict__ W, float* __restrict__ wcs) {
  int n = blockIdx.x * 256 + threadIdx.x;
  float s = 0.f;
  for (int i = 0; i < 1024; i++) s += W[(size_t)i * 1024 + n];
  wcs[n] = s;
}

// Gbsum[k] = sum_j Gb[j][k] (k<64); aux[64] = sum_j cstb[j]
__global__ __launch_bounds__(128) void k_aux(const float* __restrict__ Gb,
                                             const float* __restrict__ cstb,
                                             float* __restrict__ aux) {
  int t = threadIdx.x;
  if (t < 64) {
    float s = 0.f;
    for (int j = 0; j < 1024; j++) s += Gb[(size_t)j * 64 + t];
    aux[t] = s;
  } else if (t == 64) {
    float s = 0.f;
    for (int j = 0; j < 1024; j++) s += cstb[j];
    aux[64] = s;
  }
}

// out[128 x 128] = X @ G^T + cst, stored bf16 (cmod only)
__global__ __launch_bounds__(256) void k_bmod(const float* __restrict__ X,
                                              const float* __restrict__ G,
                                              const float* __restrict__ cst,
                                              unsigned short* __restrict__ out) {
  __shared__ __align__(16) float Xs[128 * 64];
  __shared__ __align__(16) float Gs[128 * 64];
  const int t = threadIdx.x;
  const int r0 = blockIdx.x * 128, c0 = blockIdx.y * 128;
#pragma unroll
  for (int c = 0; c < 8; ++c) {
    int i4 = c * 256 + t;
    ((float4*)Xs)[i4] = ((const float4*)(X + (size_t)r0 * 64))[i4];
    ((float4*)Gs)[i4] = ((const float4*)(G + (size_t)c0 * 64))[i4];
  }
  __syncthreads();
  const int tr = (t >> 4) * 8, tc = (t & 15) * 8;
  float acc[8][8] = {};
  for (int k = 0; k < 64; k += 4) {
    float4 xa[8], gb[8];
#pragma unroll
    for (int i = 0; i < 8; i++) xa[i] = *(const float4*)(Xs + (tr + i) * 64 + k);
#pragma unroll
    for (int j = 0; j < 8; j++) gb[j] = *(const float4*)(Gs + (tc + j) * 64 + k);
#pragma unroll
    for (int i = 0; i < 8; i++)
#pragma unroll
      for (int j = 0; j < 8; j++)
        acc[i][j] += xa[i].x * gb[j].x + xa[i].y * gb[j].y + xa[i].z * gb[j].z + xa[i].w * gb[j].w;
  }
#pragma unroll
  for (int i = 0; i < 8; i++)
#pragma unroll
    for (int j = 0; j < 8; j++)
      out[(size_t)(r0 + tr + i) * 1024 + (c0 + tc + j)] = f2bf(acc[i][j] + cst[c0 + tc + j]);
}

__global__ __launch_bounds__(256) void k_sinit(const float* __restrict__ vdata,
                                               const float* __restrict__ X,
                                               unsigned char* __restrict__ S,
                                               unsigned char* __restrict__ H,
                                               unsigned char* __restrict__ V) {
  int k = blockIdx.x * 256 + threadIdx.x;
  int r = blockIdx.y;
  if (k >= LDA) return;
  const size_t o = (size_t)r * LDA + k;
  if (k < 1024) {
    float vd = vdata[(size_t)r * 1024 + k];
    V[o] = (vd != 0.f) ? ONE8 : (unsigned char)0;
    const bool u0 = rng_u01(USALT, (unsigned)r) < 0.5f;  // == EPI1 step-0 formula
    float sv = u0 ? vd : 1.f - vd;
    S[o] = (sv != 0.f) ? ONE8 : (unsigned char)0;
  } else {
    unsigned char xv;
    if (k < 1088) xv = f2e4m3(X[(size_t)r * 64 + (k - 1024)]);
    else if (k == 1088) xv = ONE8;  // 1.0
    else xv = 0;
    S[o] = xv; H[o] = xv;
  }
}

// per-row scalar finale: sb from rank-64, d1/d2 from gemm bias-dots
__global__ __launch_bounds__(256) void k_final(
    const float* __restrict__ Xf, const float* __restrict__ aux,
    const float* __restrict__ pv0, const float* __restrict__ pv1, unsigned usalt,
    const float* __restrict__ spn_d, const float* __restrict__ spf_d,
    const float* __restrict__ spn_m, const float* __restrict__ spf_m,
    const float* __restrict__ vb_d, const float* __restrict__ vb_m,
    float* __restrict__ fdiff) {
  __shared__ float ax[65];
  int t = threadIdx.x;
  if (t < 65) ax[t] = aux[t];
  __syncthreads();
  int r = blockIdx.x * 256 + t;
  float sb = ax[64];
  const float* xr = Xf + (size_t)r * 64;
#pragma unroll
  for (int k = 0; k < 64; k++) sb += xr[k] * ax[k];
  const float dE = -pv0[r] + 2.f * pv1[r];
  const bool uu = rng_u01(usalt, (unsigned)r) < sigm(dE);
  const float d1 = vb_d[r], d2 = vb_m[r];
  float F_d = -lse2(d1 + spn_d[r], (sb - d1) + spf_d[r]);
  float vbn = uu ? d2 : (sb - d2);
  float F_m = -lse2(vbn + spn_m[r], (sb - vbn) + spf_m[r]);
  fdiff[r] = F_d - F_m;
}

__global__ __launch_bounds__(256) void k_reduce(const float* __restrict__ fdiff,
                                                float* __restrict__ out) {
  __shared__ float red[4];
  int t = threadIdx.x;
  float s = 0.f;
  for (int i = t; i < NB; i += 256) s += fdiff[i];
  for (int m = 32; m >= 1; m >>= 1) s += __shfl_xor(s, m, 64);
  if ((t & 63) == 0) red[t >> 6] = s;
  __syncthreads();
  if (t == 0) out[0] = (red[0] + red[1] + red[2] + red[3]) * (1.0f / (float)NB);
}

// ---------------------------------------------------------------------------
extern "C" void kernel_launch(void* const* d_in, const int* in_sizes, int n_in, void* d_out,
                              int out_size, void* d_ws, size_t ws_size, hipStream_t stream) {
  const float* vdata = (const float*)d_in[0];
  const float* cond = (const float*)d_in[1];
  const float* W = (const float*)d_in[2];
  const float* bb = (const float*)d_in[3];
  const float* cc = (const float*)d_in[4];
  const float* fc1w = (const float*)d_in[5];
  const float* fc1b = (const float*)d_in[6];
  const float* fc2w = (const float*)d_in[7];
  const float* fc2b = (const float*)d_in[8];
  float* out = (float*)d_out;

  char* wp = (char*)d_ws;
  auto alloc = [&](size_t bytes) {
    char* p = wp;
    wp += (bytes + 255) & ~(size_t)255;
    return p;
  };
  unsigned char* Wt = (unsigned char*)alloc((size_t)1152 * LDA);  // + bias-dot rows
  unsigned char* Wb = (unsigned char*)alloc((size_t)1024 * LDA);
  float* wcs = (float*)alloc(1024 * 4);
  float* X = (float*)alloc((size_t)NB * 64 * 4);
  float* Gb = (float*)alloc((size_t)1024 * 64 * 4);
  float* Gc = (float*)alloc((size_t)1024 * 64 * 4);
  float* cstb = (float*)alloc(1024 * 4);
  float* cstc = (float*)alloc(1024 * 4);
  float* aux = (float*)alloc(65 * 4);
  unsigned short* cmod = (unsigned short*)alloc((size_t)NB * 1024 * 2);
  unsigned char* S = (unsigned char*)alloc((size_t)NB * LDA);
  unsigned char* H = (unsigned char*)alloc((size_t)NB * LDA);
  unsigned char* V = (unsigned char*)alloc((size_t)NB * LDA);
  // per-step dE accumulators: pair t at pall + (t+1)*2*NB, t=-1..9; then 6 NB arrays
  float* pall = (float*)alloc((size_t)(KSTEPS + 1 + 3) * 2 * NB * 4);
  float* spn_d = pall + (size_t)(KSTEPS + 1) * 2 * NB;
  float* spf_d = spn_d + NB;
  float* spn_m = spf_d + NB;
  float* spf_m = spn_m + NB;
  float* vb_d = spf_m + NB;
  float* vb_m = vb_d + NB;
  float* fdiff = (float*)alloc(NB * 4);
  auto P0 = [&](int t) { return pall + (size_t)(t + 1) * 2 * NB; };
  auto P1 = [&](int t) { return pall + (size_t)(t + 1) * 2 * NB + NB; };

  hipMemsetAsync(pall, 0, (size_t)(KSTEPS + 1 + 3) * 2 * NB * 4, stream);

  k_x<<<NB * 64 / 256, 256, 0, stream>>>(cond, fc1w, fc1b, X);
  k_g<<<1024 * 64 / 256, 256, 0, stream>>>(fc2w, fc2b, bb, cc, Gb, Gc, cstb, cstc);
  k_prep<<<dim3(5, 1152), 256, 0, stream>>>(W, Gb, Gc, cstb, cstc, Wt, Wb);
  k_wcs<<<4, 256, 0, stream>>>(W, wcs);
  k_aux<<<1, 128, 0, stream>>>(Gb, cstb, aux);
  k_bmod<<<dim3(NB / 128, 8), 256, 0, stream>>>(X, Gc, cstc, cmod);
  k_sinit<<<dim3(5, NB), 256, 0, stream>>>(vdata, X, S, H, V);

  for (int step = 0; step < KSTEPS; ++step) {
    // z1 = sW + c_mod (ext-K); h ~ Bern(sigm(z1)) -> H
    gemm_bt<0><<<1024, 256, 0, stream>>>(S, Wt, H, nullptr, nullptr, nullptr, nullptr, nullptr,
                                         0u, nullptr, nullptr, nullptr,
                                         2000u + (unsigned)step, LDA);
    // z2 = hW^T + b_mod (ext-K); u_t inline; dE partials -> step t; s_new -> S
    gemm_bt<1><<<1024, 256, 0, stream>>>(H, Wb, S, nullptr, nullptr, nullptr,
                                         P0(step - 1), P1(step - 1), USALT + (unsigned)step,
                                         P0(step), P1(step), nullptr,
                                         3000u + (unsigned)step, LDA);
  }

  // Free-energy: softplus rows (tiles 0..7) + bias-dots (tile 8). K=1024.
  gemm_bt<2><<<1152, 256, 0, stream>>>(V, Wt, nullptr, cmod, wcs, X, nullptr, nullptr, 0u,
                                       spn_d, spf_d, vb_d, 0u, 1024);
  gemm_bt<2><<<1152, 256, 0, stream>>>(S, Wt, nullptr, cmod, wcs, X,
                                       P0(KSTEPS - 1), P1(KSTEPS - 1), USALT + KSTEPS,
                                       spn_m, spf_m, vb_m, 0u, 1024);
  k_final<<<NB / 256, 256, 0, stream>>>(X, aux, P0(KSTEPS - 1), P1(KSTEPS - 1), USALT + KSTEPS,
                                        spn_d, spf_d, spn_m, spf_m, vb_d, vb_m, fdiff);
  k_reduce<<<1, 256, 0, stream>>>(fdiff, out);
}